// Round 6
// baseline (222.860 us; speedup 1.0000x reference)
//
#include <hip/hip_runtime.h>
#include <math.h>
#include <stdint.h>

#define B_ROWS 2048
#define D_DIM  512
#define V_COLS 32000
#define BM 128
#define BN 128
#define BK 32
#define KSTEPS (D_DIM / BK)             // 16
#define NCT    (V_COLS / BN)            // 250 col tiles
#define S_SC   30.0f
#define COS_M  0.8775825618903728f      // cos(0.5)
#define SIN_M  0.479425538604203f       // sin(0.5)

typedef float f32x4 __attribute__((ext_vector_type(4)));

__device__ __forceinline__ void load16_to_lds(const void* g, void* l) {
  __builtin_amdgcn_global_load_lds(
      (__attribute__((address_space(1))) void*)(g),
      (__attribute__((address_space(3))) void*)(l),
      16, 0, 0);
}

// ---------- kernel 1: fused row L2-normalize (x,W) fp32 -> fp8 e4m3, + zero rowsum/out ----------
__global__ void fused_norm_kernel(const float* __restrict__ x,
                                  const float* __restrict__ W,
                                  uint8_t* __restrict__ nx,
                                  uint8_t* __restrict__ nw,
                                  float* __restrict__ rowsum,
                                  float* __restrict__ out) {
  if (blockIdx.x == 0 && threadIdx.x == 0) out[0] = 0.f;
  if (blockIdx.x < B_ROWS / 256) rowsum[blockIdx.x * 256 + threadIdx.x] = 0.f;
  const int lane = threadIdx.x & 63;
  const int wave = threadIdx.x >> 6;
  const int gr   = blockIdx.x * 4 + wave;
  const float* src;
  uint8_t* dst;
  if (gr < B_ROWS) {
    src = x + (size_t)gr * D_DIM;
    dst = nx + (size_t)gr * D_DIM;
  } else {
    src = W + (size_t)(gr - B_ROWS) * D_DIM;
    dst = nw + (size_t)(gr - B_ROWS) * D_DIM;
  }
  // lane handles 8 contiguous elems: 8*lane .. 8*lane+7
  const float4* r4 = (const float4*)src;
  float4 v0 = r4[2 * lane];
  float4 v1 = r4[2 * lane + 1];
  float ss = v0.x*v0.x + v0.y*v0.y + v0.z*v0.z + v0.w*v0.w
           + v1.x*v1.x + v1.y*v1.y + v1.z*v1.z + v1.w*v1.w;
  #pragma unroll
  for (int off = 32; off >= 1; off >>= 1) ss += __shfl_xor(ss, off, 64);
  float inv = 1.0f / fmaxf(sqrtf(ss), 1e-12f);
  int p0 = __builtin_amdgcn_cvt_pk_fp8_f32(v0.x * inv, v0.y * inv, 0, false);
  p0     = __builtin_amdgcn_cvt_pk_fp8_f32(v0.z * inv, v0.w * inv, p0, true);
  int p1 = __builtin_amdgcn_cvt_pk_fp8_f32(v1.x * inv, v1.y * inv, 0, false);
  p1     = __builtin_amdgcn_cvt_pk_fp8_f32(v1.z * inv, v1.w * inv, p1, true);
  ((int2*)dst)[lane] = make_int2(p0, p1);
}

// ---------- kernel 2: fp8 GEMM (nx @ nW^T), BARRIER-FREE wave-private pipeline ----------
// Grid: 1D 4096; ct = (id>>7)*8 + (id&7) (XCD-exclusive col tiles), rt = (id>>3)&15
//   fastest (R3/R4-proven: FETCH ~25 MB).
// Each wave owns a private 4 KB LDS region (A-half 2 KB + B-half 2 KB), double
// buffered -> NO __syncthreads anywhere. Pipeline per K-step: lgkmcnt(0) (WAR on the
// buffer about to be overwritten), issue tile k+1's 4 global_load_lds, vmcnt(4)
// (tile k resident, k+1 left in flight -- AITER pattern), compute 16 MFMA.
// Waits are inline asm with "memory" clobber = wait + compiler reordering fence.
// LDS row = 32 B of fp8; 16 B halves XOR-swizzled by row bit2 -> frag ds_read_b64
// lands 2-way bank aliasing only (free, m136).
__global__ __launch_bounds__(256, 4)
void arc_gemm_kernel(const uint8_t* __restrict__ nx,
                     const uint8_t* __restrict__ nw,
                     const int* __restrict__ labels,
                     float* __restrict__ rowsum,
                     float* __restrict__ lbl_logit) {
  __shared__ uint8_t sMem[2][4][4096];   // [buf][wave][A 0..2047 | B 2048..4095]

  const int id = blockIdx.x;
  const int ct = ((id >> 7) << 3) | (id & 7);
  if (ct >= NCT) return;
  const int rt = (id >> 3) & 15;
  const int m0 = rt * BM;
  const int n0 = ct * BN;

  const int tid  = threadIdx.x;
  const int wave = tid >> 6;
  const int lane = tid & 63;
  const int wm   = wave >> 1;
  const int wn   = wave & 1;
  const int quad = lane >> 4;
  const int l16  = lane & 15;

  // staging: instr t in {0,1} covers local rows t*32+(lane>>1); lane fetches the
  // global 16B half (lane&1)^(row bit2) so LDS slot order is the swizzled one.
  const int hoff = (((lane & 1) ^ ((lane >> 3) & 1)) << 4);
  const uint8_t* gA0 = nx + (size_t)(m0 + wm * 64 + (lane >> 1)) * D_DIM + hoff;
  const uint8_t* gB0 = nw + (size_t)(n0 + wn * 64 + (lane >> 1)) * D_DIM + hoff;

  uint8_t* const lA0 = &sMem[0][wave][0];
  uint8_t* const lA1 = &sMem[1][wave][0];
  uint8_t* const lB0 = &sMem[0][wave][2048];
  uint8_t* const lB1 = &sMem[1][wave][2048];

  // frag read offset: row l16 (+ mi*16), global 8B-chunk quad at swizzled slot
  const int sw   = ((l16 >> 2) & 1) << 1;
  const int fOff = l16 * 32 + ((quad ^ sw) << 3);

  f32x4 acc[4][4];
  #pragma unroll
  for (int i = 0; i < 4; ++i)
    #pragma unroll
    for (int j = 0; j < 4; ++j) acc[i][j] = (f32x4){0.f, 0.f, 0.f, 0.f};

  // prologue: tile 0 -> buf 0
  load16_to_lds(gA0, lA0);
  load16_to_lds(gA0 + 32 * D_DIM, lA0 + 1024);
  load16_to_lds(gB0, lB0);
  load16_to_lds(gB0 + 32 * D_DIM, lB0 + 1024);

  #pragma unroll
  for (int ks = 0; ks < KSTEPS; ++ks) {
    // WAR guard: last iteration's ds_reads (of the buffer we now overwrite) done
    asm volatile("s_waitcnt lgkmcnt(0)" ::: "memory");
    if (ks + 1 < KSTEPS) {
      uint8_t* nA = ((ks + 1) & 1) ? lA1 : lA0;
      uint8_t* nB = ((ks + 1) & 1) ? lB1 : lB0;
      const int off = (ks + 1) * BK;
      load16_to_lds(gA0 + off, nA);
      load16_to_lds(gA0 + 32 * D_DIM + off, nA + 1024);
      load16_to_lds(gB0 + off, nB);
      load16_to_lds(gB0 + 32 * D_DIM + off, nB + 1024);
      asm volatile("s_waitcnt vmcnt(4)" ::: "memory");   // tile ks resident; ks+1 in flight
    } else {
      asm volatile("s_waitcnt vmcnt(0)" ::: "memory");   // last tile resident
    }

    const uint8_t* bA = (ks & 1) ? lA1 : lA0;
    const uint8_t* bB = (ks & 1) ? lB1 : lB0;
    long a_[4], b_[4];
    #pragma unroll
    for (int mi = 0; mi < 4; ++mi) a_[mi] = *(const long*)(bA + mi * 512 + fOff);
    #pragma unroll
    for (int ni = 0; ni < 4; ++ni) b_[ni] = *(const long*)(bB + ni * 512 + fOff);
    #pragma unroll
    for (int mi = 0; mi < 4; ++mi)
      #pragma unroll
      for (int ni = 0; ni < 4; ++ni)
        acc[mi][ni] = __builtin_amdgcn_mfma_f32_16x16x32_fp8_fp8(a_[mi], b_[ni], acc[mi][ni], 0, 0, 0);
  }

  // Epilogue. C/D layout: col = lane&15, row = quad*4 + reg (dtype-independent).
  const int lblv = labels[m0 + wm * 64 + lane];
  #pragma unroll
  for (int mi = 0; mi < 4; ++mi) {
    #pragma unroll
    for (int r = 0; r < 4; ++r) {
      const int rw   = mi * 16 + quad * 4 + r;
      const int grow = m0 + wm * 64 + rw;
      const int lbl  = __shfl(lblv, rw, 64);
      float rsum = 0.f;
      #pragma unroll
      for (int ni = 0; ni < 4; ++ni) {
        float c = acc[mi][ni][r];
        const int gcol = n0 + wn * 64 + ni * 16 + l16;
        if (gcol == lbl) {
          float sy  = sqrtf(fminf(1.f, fmaxf(0.f, 1.f - c * c)));
          float phi = c * COS_M - sy * SIN_M;
          lbl_logit[grow] = S_SC * phi;           // exactly one lane grid-wide
          c = phi;
        }
        rsum += __expf(S_SC * c - 30.0f);         // fixed shift: logits in [-30,30]
      }
      #pragma unroll
      for (int off = 1; off < 16; off <<= 1)
        rsum += __shfl_xor(rsum, off, 64);
      if (l16 == 0) atomicAdd(&rowsum[grow], rsum);
    }
  }
}

// ---------- kernel 3: per-row loss + global mean ----------
__global__ void arc_finish_kernel(const float* __restrict__ rowsum,
                                  const float* __restrict__ lbl_logit,
                                  float* __restrict__ out) {
  const int row  = blockIdx.x * 256 + threadIdx.x;   // 8 blocks x 256
  const int lane = threadIdx.x & 63;
  const int wave = threadIdx.x >> 6;
  float v = (30.0f + logf(rowsum[row]) - lbl_logit[row]) * (1.0f / (float)B_ROWS);
  #pragma unroll
  for (int off = 32; off >= 1; off >>= 1) v += __shfl_xor(v, off, 64);
  __shared__ float wsum[4];
  if (lane == 0) wsum[wave] = v;
  __syncthreads();
  if (threadIdx.x == 0) atomicAdd(out, wsum[0] + wsum[1] + wsum[2] + wsum[3]);
}

// ---------- launch ----------
extern "C" void kernel_launch(void* const* d_in, const int* in_sizes, int n_in,
                              void* d_out, int out_size, void* d_ws, size_t ws_size,
                              hipStream_t stream) {
  const float* x      = (const float*)d_in[0];
  const float* W      = (const float*)d_in[1];
  const int*   labels = (const int*)d_in[2];
  float* out = (float*)d_out;

  char* ws = (char*)d_ws;
  uint8_t* nx = (uint8_t*)ws;                                       // 1 MB
  uint8_t* nw = (uint8_t*)(ws + (size_t)B_ROWS * D_DIM);            // 16.4 MB
  char* p = ws + (size_t)B_ROWS * D_DIM + (size_t)V_COLS * D_DIM;
  float* rowsum    = (float*)p;  p += (size_t)B_ROWS * 4;           // 8 KB
  float* lbl_logit = (float*)p;                                     // 8 KB

  hipLaunchKernelGGL(fused_norm_kernel, dim3((B_ROWS + V_COLS) / 4), dim3(256), 0, stream,
                     x, W, nx, nw, rowsum, out);
  hipLaunchKernelGGL(arc_gemm_kernel, dim3(32 * 16 * 8), dim3(256), 0, stream,
                     nx, nw, labels, rowsum, lbl_logit);
  hipLaunchKernelGGL(arc_finish_kernel, dim3(B_ROWS / 256), dim3(256), 0, stream,
                     rowsum, lbl_logit, out);
}